// Round 2
// baseline (668.725 us; speedup 1.0000x reference)
//
#include <hip/hip_runtime.h>
#include <hip/hip_bf16.h>

typedef __attribute__((ext_vector_type(8))) short bf16x8;
typedef __attribute__((ext_vector_type(4))) float f32x4;

#define MARGIN 0.1f

__device__ __forceinline__ unsigned short f2bf(float f) {
    unsigned int u = __builtin_bit_cast(unsigned int, f);
    u += 0x7fff + ((u >> 16) & 1);   // round-to-nearest-even (inputs are finite)
    return (unsigned short)(u >> 16);
}

// Kernel 1: L2-normalize rows of inputs -> bf16 x; neg[b] = dot(x, emb[target[b]])
__global__ __launch_bounds__(256) void prep_kernel(
    const float* __restrict__ inputs, const float* __restrict__ emb,
    const int* __restrict__ target, unsigned short* __restrict__ x_bf,
    float* __restrict__ neg)
{
    const int b = blockIdx.x;
    const int t = threadIdx.x;                    // 256 threads, 2 elems each
    const float2 v = *reinterpret_cast<const float2*>(inputs + (size_t)b * 512 + t * 2);
    const int tgt = target[b];
    const float2 e = *reinterpret_cast<const float2*>(emb + (size_t)tgt * 512 + t * 2);
    float ss = v.x * v.x + v.y * v.y;
    float de = v.x * e.x + v.y * e.y;
    #pragma unroll
    for (int off = 32; off; off >>= 1) {
        ss += __shfl_down(ss, off);
        de += __shfl_down(de, off);
    }
    __shared__ float s_ss[4], s_de[4];
    const int wid = t >> 6, lane = t & 63;
    if (lane == 0) { s_ss[wid] = ss; s_de[wid] = de; }
    __syncthreads();
    const float tss = s_ss[0] + s_ss[1] + s_ss[2] + s_ss[3];
    const float tde = s_de[0] + s_de[1] + s_de[2] + s_de[3];
    const float inv = 1.0f / fmaxf(sqrtf(tss), 1e-12f);
    const unsigned int h0 = f2bf(v.x * inv), h1 = f2bf(v.y * inv);
    *reinterpret_cast<unsigned int*>(x_bf + (size_t)b * 512 + t * 2) = h0 | (h1 << 16);
    if (t == 0) neg[b] = tde * inv;
}

// Kernel 2: per-block 64-row emb tile (f32->bf16 in LDS, full K=512, 64 KB ->
// 2 blocks/CU so one block's staging overlaps the other's compute). 8 waves
// as 4m x 2n, wave tile 64x32, 1-deep kk software pipeline, fused
// relu-margin-sum epilogue. One partial per block.
__global__ __launch_bounds__(512, 4) void gemm_loss_kernel(
    const unsigned short* __restrict__ x_bf, const float* __restrict__ emb,
    const float* __restrict__ neg, float* __restrict__ partials)
{
    __shared__ short btile[64 * 512];             // 64 KB, XOR-swizzled bf16
    char* lds = reinterpret_cast<char*>(btile);
    const int t = threadIdx.x;                    // 512 threads
    const int v0 = blockIdx.x * 64;

    // ---- stage emb tile: 64 rows x 512 cols f32 -> bf16 LDS ----
    #pragma unroll
    for (int p = 0; p < 16; ++p) {
        const int i = p * 512 + t;                // 0..8191
        const int row = i >> 7;                   // 0..63
        const int c4 = i & 127;                   // float4 column
        const float4 f = *reinterpret_cast<const float4*>(
            emb + (size_t)(v0 + row) * 512 + c4 * 4);
        const int byte = (row * 1024 + c4 * 8) ^ ((row & 7) << 4);
        ushort4 h;
        h.x = f2bf(f.x); h.y = f2bf(f.y); h.z = f2bf(f.z); h.w = f2bf(f.w);
        *reinterpret_cast<ushort4*>(lds + byte) = h;
    }
    __syncthreads();

    const int wid = t >> 6, lane = t & 63;
    const int wm = wid >> 1;                      // 0..3  (m partition)
    const int wn = wid & 1;                       // 0..1  (n partition)
    const int lrow = lane & 15;
    const int g = lane >> 4;                      // 0..3
    const int lk = g * 8;                         // k sub-offset (bf16 elems)

    float sum = 0.0f;

#define LOADA(dst, kkv)                                                        \
    {                                                                          \
        _Pragma("unroll")                                                      \
        for (int mf = 0; mf < 4; ++mf)                                         \
            dst[mf] = *reinterpret_cast<const bf16x8*>(                        \
                aptr + mf * (16 * 512) + (kkv) * 32);                          \
    }
#define LOADB(dst, kkv)                                                        \
    {                                                                          \
        _Pragma("unroll")                                                      \
        for (int nf = 0; nf < 2; ++nf) {                                       \
            const int vloc = wn * 32 + nf * 16 + lrow;                         \
            const int byte = (vloc * 1024 + ((kkv) * 32 + lk) * 2)             \
                             ^ ((vloc & 7) << 4);                              \
            dst[nf] = *reinterpret_cast<const bf16x8*>(lds + byte);            \
        }                                                                      \
    }
#define DOMFMA(a, b)                                                           \
    {                                                                          \
        _Pragma("unroll")                                                      \
        for (int mf = 0; mf < 4; ++mf)                                         \
            _Pragma("unroll")                                                  \
            for (int nf = 0; nf < 2; ++nf)                                     \
                acc[mf][nf] = __builtin_amdgcn_mfma_f32_16x16x32_bf16(         \
                    a[mf], b[nf], acc[mf][nf], 0, 0, 0);                       \
    }

    #pragma unroll 1
    for (int mc = 0; mc < 4; ++mc) {
        const int mbase = mc * 256 + wm * 64;
        f32x4 acc[4][2];
        #pragma unroll
        for (int i = 0; i < 4; ++i)
            #pragma unroll
            for (int j = 0; j < 2; ++j) acc[i][j] = (f32x4)(0.0f);

        const unsigned short* aptr = x_bf + (size_t)(mbase + lrow) * 512 + lk;

        bf16x8 a0[4], b0[2], a1[4], b1[2];
        LOADA(a0, 0); LOADB(b0, 0);
        #pragma unroll
        for (int kk = 0; kk < 16; kk += 2) {
            LOADA(a1, kk + 1); LOADB(b1, kk + 1);
            DOMFMA(a0, b0);
            if (kk + 2 < 16) { LOADA(a0, kk + 2); LOADB(b0, kk + 2); }
            DOMFMA(a1, b1);
        }

        // ---- fused epilogue: relu(margin + dot - neg[m]) summed ----
        #pragma unroll
        for (int mf = 0; mf < 4; ++mf) {
            const float4 nv = *reinterpret_cast<const float4*>(
                neg + mbase + mf * 16 + g * 4);
            #pragma unroll
            for (int j = 0; j < 4; ++j) {
                const float nvj = (&nv.x)[j];
                #pragma unroll
                for (int nf = 0; nf < 2; ++nf)
                    sum += fmaxf(MARGIN + acc[mf][nf][j] - nvj, 0.0f);
            }
        }
    }

    // ---- block reduction (reuse LDS after barrier) ----
    __syncthreads();
    #pragma unroll
    for (int off = 32; off; off >>= 1) sum += __shfl_down(sum, off);
    float* red = reinterpret_cast<float*>(lds);
    if (lane == 0) red[wid] = sum;
    __syncthreads();
    if (t == 0) {
        float tot = 0.f;
        #pragma unroll
        for (int w = 0; w < 8; ++w) tot += red[w];
        partials[blockIdx.x] = tot;
    }
}

// Kernel 3: deterministic final reduction of 2000 block partials, mean over B.
__global__ __launch_bounds__(256) void reduce_kernel(
    const float* __restrict__ partials, float* __restrict__ out)
{
    float s = 0.f;
    for (int i = threadIdx.x; i < 2000; i += 256) s += partials[i];
    #pragma unroll
    for (int off = 32; off; off >>= 1) s += __shfl_down(s, off);
    __shared__ float red[4];
    const int wid = threadIdx.x >> 6, lane = threadIdx.x & 63;
    if (lane == 0) red[wid] = s;
    __syncthreads();
    if (threadIdx.x == 0)
        out[0] = (red[0] + red[1] + red[2] + red[3]) * (1.0f / 1024.0f);
}

extern "C" void kernel_launch(void* const* d_in, const int* in_sizes, int n_in,
                              void* d_out, int out_size, void* d_ws, size_t ws_size,
                              hipStream_t stream)
{
    const float* inputs = (const float*)d_in[0];
    const float* emb    = (const float*)d_in[1];
    const int*   target = (const int*)d_in[2];
    float* out = (float*)d_out;
    char*  ws  = (char*)d_ws;

    unsigned short* x_bf  = (unsigned short*)ws;                    // 1 MB
    float*          neg   = (float*)(ws + (1 << 20));               // 4 KB
    float*          parts = (float*)(ws + (1 << 20) + (1 << 14));   // 8 KB

    prep_kernel<<<1024, 256, 0, stream>>>(inputs, emb, target, x_bf, neg);
    gemm_loss_kernel<<<2000, 512, 0, stream>>>(x_bf, emb, neg, parts);
    reduce_kernel<<<1, 256, 0, stream>>>(parts, out);
}

// Round 3
// 256.785 us; speedup vs baseline: 2.6042x; 2.6042x over previous
//
#include <hip/hip_runtime.h>

typedef __attribute__((ext_vector_type(4))) float f32x4;

#define MARGIN 0.1f

// Kernel 1: L2-normalize rows of inputs -> fp8 e4m3 x; neg[b] = f32 dot(x, emb[target[b]])
__global__ __launch_bounds__(256) void prep_kernel(
    const float* __restrict__ inputs, const float* __restrict__ emb,
    const int* __restrict__ target, unsigned char* __restrict__ x_fp8,
    float* __restrict__ neg)
{
    const int b = blockIdx.x;
    const int t = threadIdx.x;                    // 256 threads, 2 elems each
    const float2 v = *reinterpret_cast<const float2*>(inputs + (size_t)b * 512 + t * 2);
    const int tgt = target[b];
    const float2 e = *reinterpret_cast<const float2*>(emb + (size_t)tgt * 512 + t * 2);
    float ss = v.x * v.x + v.y * v.y;
    float de = v.x * e.x + v.y * e.y;
    #pragma unroll
    for (int off = 32; off; off >>= 1) {
        ss += __shfl_down(ss, off);
        de += __shfl_down(de, off);
    }
    __shared__ float s_ss[4], s_de[4];
    const int wid = t >> 6, lane = t & 63;
    if (lane == 0) { s_ss[wid] = ss; s_de[wid] = de; }
    __syncthreads();
    const float tss = s_ss[0] + s_ss[1] + s_ss[2] + s_ss[3];
    const float tde = s_de[0] + s_de[1] + s_de[2] + s_de[3];
    const float inv = 1.0f / fmaxf(sqrtf(tss), 1e-12f);
    // pack two e4m3 bytes (HW RNE conversion)
    const int pk = __builtin_amdgcn_cvt_pk_fp8_f32(v.x * inv, v.y * inv, 0, false);
    *reinterpret_cast<unsigned short*>(x_fp8 + (size_t)b * 512 + t * 2) =
        (unsigned short)(pk & 0xffff);
    if (t == 0) neg[b] = tde * inv;
}

// Kernel 2: per-block 64-row emb tile as fp8 in LDS (32 KB, bank-optimal XOR
// swizzle). 8 waves, each owns 64 m-rows (8m x 1n -> zero A redundancy) and
// the full 64-col n-tile (nf=4). Two m-passes cover M=1024. A (x_fp8)
// streamed from L2 as 8B loads. Fused relu-margin-sum epilogue.
__global__ __launch_bounds__(512, 4) void gemm_loss_kernel(
    const unsigned char* __restrict__ x_fp8, const float* __restrict__ emb,
    const float* __restrict__ neg, float* __restrict__ partials)
{
    __shared__ unsigned char btile[64 * 512];     // 32 KB fp8, swizzled
    const int t = threadIdx.x;                    // 512 threads
    const int v0 = blockIdx.x * 64;

    // ---- stage emb tile: 64 rows x 512 cols f32 -> fp8 LDS ----
    #pragma unroll
    for (int p = 0; p < 16; ++p) {
        const int i = p * 512 + t;                // 0..8191
        const int row = i >> 7;                   // 0..63
        const int c4 = i & 127;                   // float4 column
        const float4 f = *reinterpret_cast<const float4*>(
            emb + (size_t)(v0 + row) * 512 + c4 * 4);
        int u = __builtin_amdgcn_cvt_pk_fp8_f32(f.x, f.y, 0, false);
        u = __builtin_amdgcn_cvt_pk_fp8_f32(f.z, f.w, u, true);
        const int byte = (row * 512 + c4 * 4) ^ ((row & 15) << 3);
        *reinterpret_cast<int*>(btile + byte) = u;
    }
    __syncthreads();

    const int wid = t >> 6, lane = t & 63;
    const int lrow = lane & 15;                   // A row / B row within frag
    const int g = lane >> 4;                      // k-group 0..3 (8 elems each)

    float sum = 0.0f;

    #pragma unroll 1
    for (int mc = 0; mc < 2; ++mc) {
        const int mbase = mc * 512 + wid * 64;    // this wave's 64 m-rows
        f32x4 acc[4][4];
        #pragma unroll
        for (int i = 0; i < 4; ++i)
            #pragma unroll
            for (int j = 0; j < 4; ++j) acc[i][j] = (f32x4)(0.0f);

        const unsigned char* aptr = x_fp8 + (size_t)(mbase + lrow) * 512 + g * 8;

        #pragma unroll 4
        for (int kk = 0; kk < 16; ++kk) {
            long long a[4], b[4];
            #pragma unroll
            for (int mf = 0; mf < 4; ++mf)
                a[mf] = *reinterpret_cast<const long long*>(
                    aptr + mf * (16 * 512) + kk * 32);
            #pragma unroll
            for (int nf = 0; nf < 4; ++nf) {
                const int vloc = nf * 16 + lrow;
                const int byte = (vloc * 512 + kk * 32 + g * 8) ^ ((vloc & 15) << 3);
                b[nf] = *reinterpret_cast<const long long*>(btile + byte);
            }
            #pragma unroll
            for (int mf = 0; mf < 4; ++mf)
                #pragma unroll
                for (int nf = 0; nf < 4; ++nf)
                    acc[mf][nf] = __builtin_amdgcn_mfma_f32_16x16x32_fp8_fp8(
                        a[mf], b[nf], acc[mf][nf], 0, 0, 0);
        }

        // ---- fused epilogue: relu(margin + dot - neg[m]) summed ----
        #pragma unroll
        for (int mf = 0; mf < 4; ++mf) {
            const float4 nv = *reinterpret_cast<const float4*>(
                neg + mbase + mf * 16 + g * 4);
            #pragma unroll
            for (int j = 0; j < 4; ++j) {
                const float nvj = (&nv.x)[j];
                #pragma unroll
                for (int nf = 0; nf < 4; ++nf)
                    sum += fmaxf(MARGIN + acc[mf][nf][j] - nvj, 0.0f);
            }
        }
    }

    // ---- block reduction (reuse LDS after barrier) ----
    __syncthreads();
    #pragma unroll
    for (int off = 32; off; off >>= 1) sum += __shfl_down(sum, off);
    float* red = reinterpret_cast<float*>(btile);
    if (lane == 0) red[wid] = sum;
    __syncthreads();
    if (t == 0) {
        float tot = 0.f;
        #pragma unroll
        for (int w = 0; w < 8; ++w) tot += red[w];
        partials[blockIdx.x] = tot;
    }
}

// Kernel 3: deterministic final reduction of 2000 block partials, mean over B.
__global__ __launch_bounds__(256) void reduce_kernel(
    const float* __restrict__ partials, float* __restrict__ out)
{
    float s = 0.f;
    for (int i = threadIdx.x; i < 2000; i += 256) s += partials[i];
    #pragma unroll
    for (int off = 32; off; off >>= 1) s += __shfl_down(s, off);
    __shared__ float red[4];
    const int wid = threadIdx.x >> 6, lane = threadIdx.x & 63;
    if (lane == 0) red[wid] = s;
    __syncthreads();
    if (threadIdx.x == 0)
        out[0] = (red[0] + red[1] + red[2] + red[3]) * (1.0f / 1024.0f);
}

extern "C" void kernel_launch(void* const* d_in, const int* in_sizes, int n_in,
                              void* d_out, int out_size, void* d_ws, size_t ws_size,
                              hipStream_t stream)
{
    const float* inputs = (const float*)d_in[0];
    const float* emb    = (const float*)d_in[1];
    const int*   target = (const int*)d_in[2];
    float* out = (float*)d_out;
    char*  ws  = (char*)d_ws;

    unsigned char* x_fp8 = (unsigned char*)ws;                      // 512 KB
    float*         neg   = (float*)(ws + (512 << 10));              // 4 KB
    float*         parts = (float*)(ws + (512 << 10) + (1 << 14));  // 8 KB

    prep_kernel<<<1024, 256, 0, stream>>>(inputs, emb, target, x_fp8, neg);
    gemm_loss_kernel<<<2000, 512, 0, stream>>>(x_fp8, emb, neg, parts);
    reduce_kernel<<<1, 256, 0, stream>>>(parts, out);
}

// Round 4
// 155.662 us; speedup vs baseline: 4.2960x; 1.6496x over previous
//
#include <hip/hip_runtime.h>

typedef __attribute__((ext_vector_type(4))) float f32x4;
typedef __attribute__((ext_vector_type(2))) long long llx2;

#define MARGIN 0.1f

__device__ __forceinline__ void gload_lds16(const void* g, void* l) {
    __builtin_amdgcn_global_load_lds(
        (const __attribute__((address_space(1))) unsigned int*)g,
        (__attribute__((address_space(3))) unsigned int*)l, 16, 0, 0);
}

// Kernel 1: L2-normalize rows of inputs -> fp8 x in BOTH row-major (fallback)
// and MFMA-fragment-major (primary) layouts; neg[b] = f32 dot(x, emb[target[b]]).
__global__ __launch_bounds__(256) void prep_kernel(
    const float* __restrict__ inputs, const float* __restrict__ emb,
    const int* __restrict__ target, unsigned short* __restrict__ x_frag,
    unsigned char* __restrict__ x_row, float* __restrict__ neg)
{
    const int b = blockIdx.x;
    const int t = threadIdx.x;                    // 256 threads, 2 elems each
    const float2 v = *reinterpret_cast<const float2*>(inputs + (size_t)b * 512 + t * 2);
    const int tgt = target[b];
    const float2 e = *reinterpret_cast<const float2*>(emb + (size_t)tgt * 512 + t * 2);
    float ss = v.x * v.x + v.y * v.y;
    float de = v.x * e.x + v.y * e.y;
    #pragma unroll
    for (int off = 32; off; off >>= 1) {
        ss += __shfl_down(ss, off);
        de += __shfl_down(de, off);
    }
    __shared__ float s_ss[4], s_de[4];
    const int wid = t >> 6, lane = t & 63;
    if (lane == 0) { s_ss[wid] = ss; s_de[wid] = de; }
    __syncthreads();
    const float tss = s_ss[0] + s_ss[1] + s_ss[2] + s_ss[3];
    const float tde = s_de[0] + s_de[1] + s_de[2] + s_de[3];
    const float inv = 1.0f / fmaxf(sqrtf(tss), 1e-12f);
    const int pk = __builtin_amdgcn_cvt_pk_fp8_f32(v.x * inv, v.y * inv, 0, false);
    const unsigned short pk16 = (unsigned short)(pk & 0xffff);
    // row-major (fallback path)
    *reinterpret_cast<unsigned short*>(x_row + (size_t)b * 512 + 2 * t) = pk16;
    // fragment-major (primary path): A-frag for 16x16x32: lane l holds
    // A[row=l&15][k=(l>>4)*8 + 0..7]; addr = f*8192 + lane*128 + kk*8 + byte
    const int f    = b >> 4;
    const int flan = (b & 15) | (((t >> 2) & 3) << 4);
    const int kk   = t >> 4;
    const int byt  = (2 * t) & 7;
    x_frag[(f * 8192 + flan * 128 + kk * 8 + byt) >> 1] = pk16;
    if (t == 0) neg[b] = tde * inv;
}

// Kernel 1b (primary): convert emb f32 -> fp8 e4m3 in fragment-major tile
// layout: addr = tile*32768 + kk*2048 + col*32 + g*8 + byte (col = row-in-tile).
__global__ __launch_bounds__(256) void convert_kernel(
    const float* __restrict__ emb, unsigned char* __restrict__ emb8)
{
    const int nt = blockIdx.x, t = threadIdx.x;
    const size_t src = (size_t)(nt * 64 + (t >> 2)) * 512 + (t & 3) * 8;
    unsigned char* dst = emb8 + (size_t)nt * 32768 + t * 8;
    #pragma unroll 4
    for (int i = 0; i < 16; ++i) {
        const float4 f0 = *reinterpret_cast<const float4*>(emb + src + i * 32);
        const float4 f1 = *reinterpret_cast<const float4*>(emb + src + i * 32 + 4);
        int u0 = __builtin_amdgcn_cvt_pk_fp8_f32(f0.x, f0.y, 0, false);
        u0 = __builtin_amdgcn_cvt_pk_fp8_f32(f0.z, f0.w, u0, true);
        int u1 = __builtin_amdgcn_cvt_pk_fp8_f32(f1.x, f1.y, 0, false);
        u1 = __builtin_amdgcn_cvt_pk_fp8_f32(f1.z, f1.w, u1, true);
        *reinterpret_cast<uint2*>(dst + i * 2048) = make_uint2((unsigned)u0, (unsigned)u1);
    }
}

// Kernel 2 (primary): A (x) resident in registers (128 VGPR: 4 frags x 16 kk),
// emb fp8 tiles streamed through double-buffered LDS via global_load_lds with
// counted vmcnt + raw s_barrier (no syncthreads drain). Inner loop: 4
// ds_read_b64 + 16 MFMA only. Each block: one m-half (512 rows), 15-16 n-tiles.
__global__ __launch_bounds__(512, 2) void gemm_frag_kernel(
    const unsigned short* __restrict__ x_frag, const unsigned char* __restrict__ emb8,
    const float* __restrict__ neg, float* __restrict__ partials)
{
    __shared__ unsigned char btile[65536];        // 2 x 32 KB double buffer
    const int t = threadIdx.x;
    const int wid = t >> 6, lane = t & 63;
    const int lrow = lane & 15, g = lane >> 4;
    const int bx = blockIdx.x;
    // pair blocks (same group, both m-halves) 8 apart -> same XCD L2
    const int group = (bx & 7) | ((bx >> 4) << 3);     // 0..127
    const int mhalf = (bx >> 3) & 1;
    const int cnt = (group < 80) ? 16 : 15;            // 80*16 + 48*15 = 2000

    // ---- A prologue: this wave's 64 m-rows, full K, into registers ----
    long long areg[4][16];                             // 128 VGPR
    #pragma unroll
    for (int mf = 0; mf < 4; ++mf) {
        const int f = mhalf * 32 + wid * 4 + mf;
        const llx2* base = reinterpret_cast<const llx2*>(
            x_frag + ((f * 8192 + lane * 128) >> 1));
        #pragma unroll
        for (int i = 0; i < 8; ++i)
            *reinterpret_cast<llx2*>(&areg[mf][2 * i]) = base[i];
    }

#define STAGE(buf, tile)                                                      \
    {                                                                         \
        const size_t gb = (size_t)(tile) * 32768 + wid * 4096 + lane * 16;    \
        _Pragma("unroll")                                                     \
        for (int p = 0; p < 4; ++p)                                           \
            gload_lds16(emb8 + gb + p * 1024,                                 \
                        &btile[(buf) * 32768 + wid * 4096 + p * 1024]);       \
    }

    STAGE(0, group);                                   // tile j=0
    float sum = 0.0f;
    const char* lbase = reinterpret_cast<const char*>(btile) + lrow * 32 + g * 8;

    #pragma unroll 1
    for (int j = 0; j < cnt; ++j) {
        if (j + 1 < cnt) {
            STAGE((j + 1) & 1, group + 128 * (j + 1));
            asm volatile("s_waitcnt vmcnt(4)" ::: "memory");
        } else {
            asm volatile("s_waitcnt vmcnt(0)" ::: "memory");
        }
        __builtin_amdgcn_s_barrier();                  // buf[j&1] staged for all
        __builtin_amdgcn_sched_barrier(0);

        f32x4 acc[4][4];
        #pragma unroll
        for (int i = 0; i < 4; ++i)
            #pragma unroll
            for (int k = 0; k < 4; ++k) acc[i][k] = (f32x4)(0.0f);

        const char* bb = lbase + (j & 1) * 32768;
        #pragma unroll
        for (int kk = 0; kk < 16; ++kk) {
            long long bfr[4];
            #pragma unroll
            for (int nf = 0; nf < 4; ++nf)
                bfr[nf] = *reinterpret_cast<const long long*>(
                    bb + kk * 2048 + nf * 512);
            #pragma unroll
            for (int mf = 0; mf < 4; ++mf)
                #pragma unroll
                for (int nf = 0; nf < 4; ++nf)
                    acc[mf][nf] = __builtin_amdgcn_mfma_f32_16x16x32_fp8_fp8(
                        areg[mf][kk], bfr[nf], acc[mf][nf], 0, 0, 0);
        }

        // ---- fused epilogue: relu(margin + dot - neg[m]) summed ----
        const int rbase = mhalf * 512 + wid * 64 + g * 4;
        #pragma unroll
        for (int mf = 0; mf < 4; ++mf) {
            const float4 nv = *reinterpret_cast<const float4*>(neg + rbase + mf * 16);
            #pragma unroll
            for (int jj = 0; jj < 4; ++jj) {
                const float nvj = (&nv.x)[jj];
                #pragma unroll
                for (int nf = 0; nf < 4; ++nf)
                    sum += fmaxf(MARGIN + acc[mf][nf][jj] - nvj, 0.0f);
            }
        }
        __builtin_amdgcn_sched_barrier(0);
        __builtin_amdgcn_s_barrier();                  // all done reading buf[j&1]
    }

    // ---- block reduction ----
    __syncthreads();
    #pragma unroll
    for (int off = 32; off; off >>= 1) sum += __shfl_down(sum, off);
    float* red = reinterpret_cast<float*>(btile);
    if (lane == 0) red[wid] = sum;
    __syncthreads();
    if (t == 0) {
        float tot = 0.f;
        #pragma unroll
        for (int w = 0; w < 8; ++w) tot += red[w];
        partials[bx] = tot;
    }
}

// Kernel 2 (fallback, R3 verbatim): used when ws too small for emb_fp8.
__global__ __launch_bounds__(512, 4) void gemm_loss_fallback(
    const unsigned char* __restrict__ x_fp8, const float* __restrict__ emb,
    const float* __restrict__ neg, float* __restrict__ partials)
{
    __shared__ unsigned char btile[64 * 512];
    const int t = threadIdx.x;
    const int v0 = blockIdx.x * 64;
    #pragma unroll
    for (int p = 0; p < 16; ++p) {
        const int i = p * 512 + t;
        const int row = i >> 7;
        const int c4 = i & 127;
        const float4 f = *reinterpret_cast<const float4*>(
            emb + (size_t)(v0 + row) * 512 + c4 * 4);
        int u = __builtin_amdgcn_cvt_pk_fp8_f32(f.x, f.y, 0, false);
        u = __builtin_amdgcn_cvt_pk_fp8_f32(f.z, f.w, u, true);
        const int byte = (row * 512 + c4 * 4) ^ ((row & 15) << 3);
        *reinterpret_cast<int*>(btile + byte) = u;
    }
    __syncthreads();
    const int wid = t >> 6, lane = t & 63;
    const int lrow = lane & 15;
    const int g = lane >> 4;
    float sum = 0.0f;
    #pragma unroll 1
    for (int mc = 0; mc < 2; ++mc) {
        const int mbase = mc * 512 + wid * 64;
        f32x4 acc[4][4];
        #pragma unroll
        for (int i = 0; i < 4; ++i)
            #pragma unroll
            for (int j = 0; j < 4; ++j) acc[i][j] = (f32x4)(0.0f);
        const unsigned char* aptr = x_fp8 + (size_t)(mbase + lrow) * 512 + g * 8;
        #pragma unroll 4
        for (int kk = 0; kk < 16; ++kk) {
            long long a[4], b[4];
            #pragma unroll
            for (int mf = 0; mf < 4; ++mf)
                a[mf] = *reinterpret_cast<const long long*>(
                    aptr + mf * (16 * 512) + kk * 32);
            #pragma unroll
            for (int nf = 0; nf < 4; ++nf) {
                const int vloc = nf * 16 + lrow;
                const int byte = (vloc * 512 + kk * 32 + g * 8) ^ ((vloc & 15) << 3);
                b[nf] = *reinterpret_cast<const long long*>(btile + byte);
            }
            #pragma unroll
            for (int mf = 0; mf < 4; ++mf)
                #pragma unroll
                for (int nf = 0; nf < 4; ++nf)
                    acc[mf][nf] = __builtin_amdgcn_mfma_f32_16x16x32_fp8_fp8(
                        a[mf], b[nf], acc[mf][nf], 0, 0, 0);
        }
        #pragma unroll
        for (int mf = 0; mf < 4; ++mf) {
            const float4 nv = *reinterpret_cast<const float4*>(
                neg + mbase + mf * 16 + g * 4);
            #pragma unroll
            for (int j = 0; j < 4; ++j) {
                const float nvj = (&nv.x)[j];
                #pragma unroll
                for (int nf = 0; nf < 4; ++nf)
                    sum += fmaxf(MARGIN + acc[mf][nf][j] - nvj, 0.0f);
            }
        }
    }
    __syncthreads();
    #pragma unroll
    for (int off = 32; off; off >>= 1) sum += __shfl_down(sum, off);
    float* red = reinterpret_cast<float*>(btile);
    if (lane == 0) red[wid] = sum;
    __syncthreads();
    if (t == 0) {
        float tot = 0.f;
        #pragma unroll
        for (int w = 0; w < 8; ++w) tot += red[w];
        partials[blockIdx.x] = tot;
    }
}

// Kernel 3: deterministic final reduction of n block partials, mean over B.
__global__ __launch_bounds__(256) void reduce_kernel(
    const float* __restrict__ partials, float* __restrict__ out, int n)
{
    float s = 0.f;
    for (int i = threadIdx.x; i < n; i += 256) s += partials[i];
    #pragma unroll
    for (int off = 32; off; off >>= 1) s += __shfl_down(s, off);
    __shared__ float red[4];
    const int wid = threadIdx.x >> 6, lane = threadIdx.x & 63;
    if (lane == 0) red[wid] = s;
    __syncthreads();
    if (threadIdx.x == 0)
        out[0] = (red[0] + red[1] + red[2] + red[3]) * (1.0f / 1024.0f);
}

extern "C" void kernel_launch(void* const* d_in, const int* in_sizes, int n_in,
                              void* d_out, int out_size, void* d_ws, size_t ws_size,
                              hipStream_t stream)
{
    const float* inputs = (const float*)d_in[0];
    const float* emb    = (const float*)d_in[1];
    const int*   target = (const int*)d_in[2];
    float* out = (float*)d_out;
    char*  ws  = (char*)d_ws;

    unsigned short* x_frag = (unsigned short*)ws;                   // 512 KB
    unsigned char*  x_row  = (unsigned char*)(ws + 524288);         // 512 KB
    float*          neg    = (float*)(ws + 1048576);                // 4 KB
    float*          parts  = (float*)(ws + 1056768);                // 8 KB
    unsigned char*  emb8   = (unsigned char*)(ws + 2097152);        // 65.5 MB

    const size_t need = 2097152ULL + 65536000ULL;
    const bool big = ws_size >= need;

    prep_kernel<<<1024, 256, 0, stream>>>(inputs, emb, target, x_frag, x_row, neg);
    if (big) {
        convert_kernel<<<2000, 256, 0, stream>>>(emb, emb8);
        gemm_frag_kernel<<<256, 512, 0, stream>>>(x_frag, emb8, neg, parts);
        reduce_kernel<<<1, 256, 0, stream>>>(parts, out, 256);
    } else {
        gemm_loss_fallback<<<2000, 512, 0, stream>>>(x_row, emb, neg, parts);
        reduce_kernel<<<1, 256, 0, stream>>>(parts, out, 2000);
    }
}